// Round 10
// baseline (135.671 us; speedup 1.0000x reference)
//
#include <hip/hip_runtime.h>
#include <hip/hip_bf16.h>

// MultiHeadAttention: B=4 H=12 S=2048 D=64 E=768, causal. fp32 in/out, bf16 MFMA compute.
// R9: GEMMs get depth-3 pipelines (triple-buffered LDS, WAITBAR(16) -> 2 tiles in
//     flight, ~2 iters of latency cover). Structure otherwise identical to R8.

typedef __attribute__((ext_vector_type(8))) short bf16x8;
typedef __attribute__((ext_vector_type(4))) float f32x4;
typedef __attribute__((ext_vector_type(16))) float f32x16;
typedef __attribute__((ext_vector_type(4))) uint u32x4;

// ws offsets in bf16 elements
#define OFF_XB   0            // 8192*768            = 6291456
#define OFF_WT   6291456      // 3 * 12*64*768       = 1769472
#define OFF_WPT  8060928      // 768*768             =  589824
#define OFF_QKV  8650752      // q,k: 2 * 6291456; then vt (uints)
#define OFF_AO   27525120     // 8192*768            = 6291456

#define SCALE_LOG2E 0.1803368801111204f   // (1/8) * log2(e)

__device__ inline ushort f2bf(float f) {
  __hip_bfloat16 h = __float2bfloat16(f);
  return *reinterpret_cast<ushort*>(&h);
}
__device__ inline uint cvt_pk(float lo, float hi) {
  uint r;
  asm("v_cvt_pk_bf16_f32 %0, %1, %2" : "=v"(r) : "v"(lo), "v"(hi));
  return r;
}
#define GLOAD16(g, l)                                                              \
  __builtin_amdgcn_global_load_lds(                                                \
      (const __attribute__((address_space(1))) uint*)(g),                          \
      (__attribute__((address_space(3))) uint*)(l), 16, 0, 0)

// counted-wait + barrier, memory-fenced so the compiler can't add its own drain
#define WAITBAR(n) asm volatile("s_waitcnt vmcnt(" #n ")\ns_barrier" ::: "memory")
#define ENDBAR()   asm volatile("s_waitcnt lgkmcnt(0)\ns_barrier" ::: "memory")

// ---------- fp32 -> bf16 bulk convert (8 elems/thread)
__global__ __launch_bounds__(256) void cvt_bf16(const float* __restrict__ src,
                                                ushort* __restrict__ dst, int n8) {
  int i = blockIdx.x * 256 + threadIdx.x;
  if (i >= n8) return;
  float4 a = *(const float4*)&src[(size_t)i * 8];
  float4 b = *(const float4*)&src[(size_t)i * 8 + 4];
  u32x4 pk = {cvt_pk(a.x, a.y), cvt_pk(a.z, a.w), cvt_pk(b.x, b.y), cvt_pk(b.z, b.w)};
  *(bf16x8*)&dst[(size_t)i * 8] = __builtin_bit_cast(bf16x8, pk);
}

// ---------- tiled 64x64 transpose+convert for the three QKV weights (y = mat 0..35)
__global__ __launch_bounds__(256) void transpose_wqkv(const float* __restrict__ Wq,
                                                      const float* __restrict__ Wk,
                                                      const float* __restrict__ Wv,
                                                      ushort* __restrict__ dst) {
  __shared__ ushort tile[64][130];
  int mat = blockIdx.y;       // 0..35
  int te = blockIdx.x;        // 0..11 (E tiles); Ddim = 64 -> single d tile
  const float* src = (mat < 12) ? Wq : (mat < 24) ? Wk : Wv;
  int m12 = mat % 12;
  size_t base = (size_t)m12 * 768 * 64;
  int t = threadIdx.x;
#pragma unroll
  for (int i = 0; i < 16; i++) {
    int idx = i * 256 + t;
    int r = idx >> 6, c = idx & 63;
    tile[r][c] = f2bf(src[base + (size_t)(te * 64 + r) * 64 + c]);
  }
  __syncthreads();
  size_t obase = (size_t)mat * 49152;  // 64*768
#pragma unroll
  for (int i = 0; i < 16; i++) {
    int idx = i * 256 + t;
    int c = idx >> 6, r = idx & 63;
    dst[obase + (size_t)c * 768 + te * 64 + r] = tile[r][c];
  }
}

// ---------- tiled 64x64 transpose+convert: fp32 [Edim][Ddim] -> bf16 [Ddim][Edim]
__global__ __launch_bounds__(256) void transpose_w(const float* __restrict__ src,
                                                   ushort* __restrict__ dst,
                                                   int Edim, int Ddim) {
  __shared__ ushort tile[64][130];
  int ntd = Ddim >> 6;
  int te = blockIdx.x / ntd, td = blockIdx.x % ntd;
  int t = threadIdx.x;
#pragma unroll
  for (int i = 0; i < 16; i++) {
    int idx = i * 256 + t;
    int r = idx >> 6, c = idx & 63;
    tile[r][c] = f2bf(src[(size_t)(te * 64 + r) * Ddim + td * 64 + c]);
  }
  __syncthreads();
#pragma unroll
  for (int i = 0; i < 16; i++) {
    int idx = i * 256 + t;
    int c = idx >> 6, r = idx & 63;
    dst[(size_t)(td * 64 + c) * Edim + te * 64 + r] = tile[r][c];
  }
}

// swizzle term for row (row multiple-of-16 bases drop out): ((row + (row>>2)) & 3)
__device__ inline uint swz(uint row) { return (row + (row >> 2)) & 3; }

// ---------- QKV GEMM: xb[8192,768] @ Wt(2304x768) -> q,k,vt
// grid (64, 18), 128 thr = 2 waves; wave w owns rows w*64, all 128 cols.
// Depth-3 counted-vmcnt pipeline: 3 LDS buffers, 2 tiles (16 loads) in flight at wait.
__global__ __launch_bounds__(128, 2) void gemm_qkv(const ushort* __restrict__ X,
                                                   const ushort* __restrict__ Wt,
                                                   ushort* __restrict__ qkv,
                                                   uint* __restrict__ vtg) {
  __shared__ ushort Ash[3][128 * 32];
  __shared__ ushort Bsh[3][128 * 32];
  int mb = blockIdx.x, nb = blockIdx.y;
  int t = threadIdx.x, w = t >> 6, lane = t & 63, lo = lane & 15, g = lane >> 4;
  const ushort* Ab = X + (size_t)mb * 128 * 768;
  const ushort* Bb = Wt + (size_t)nb * 128 * 768;
  f32x4 acc[4][8];
#pragma unroll
  for (int fi = 0; fi < 4; fi++)
#pragma unroll
    for (int fj = 0; fj < 8; fj++) acc[fi][fj] = (f32x4){0.f, 0.f, 0.f, 0.f};
  // staging source mapping: 4 chunks each for A and B per tile
  uint srow[4], ssc[4];
#pragma unroll
  for (int j = 0; j < 4; j++) {
    uint ci = j * 128 + t;
    srow[j] = ci >> 2;
    ssc[j] = ((ci & 3) ^ swz(ci >> 2)) << 4;
  }

#define QKV_STAGE(tile, bsel)                                                         \
  {                                                                                   \
    int e0 = (tile) * 32;                                                             \
    _Pragma("unroll")                                                                 \
    for (int j = 0; j < 4; j++) {                                                     \
      GLOAD16((const char*)(Ab + (size_t)srow[j] * 768 + e0) + ssc[j],                \
              &Ash[bsel][(j * 128 + w * 64) * 8]);                                    \
      GLOAD16((const char*)(Bb + (size_t)srow[j] * 768 + e0) + ssc[j],                \
              &Bsh[bsel][(j * 128 + w * 64) * 8]);                                    \
    }                                                                                 \
  }

  QKV_STAGE(0, 0);
  QKV_STAGE(1, 1);
  QKV_STAGE(2, 2);
  uint rsw = swz(lo) << 4;
  for (int it = 0; it < 24; ++it) {
    if (it <= 21) { WAITBAR(16); } else if (it == 22) { WAITBAR(8); } else { WAITBAR(0); }
    int bsel = it % 3;
    const ushort* Acur = Ash[bsel];
    const ushort* Bcur = Bsh[bsel];
    bf16x8 af[4], bf[8];
#pragma unroll
    for (int fi = 0; fi < 4; fi++) {
      int arow = w * 64 + fi * 16 + lo;
      af[fi] = *(const bf16x8*)((const char*)Acur + arow * 64 + ((g << 4) ^ rsw));
    }
#pragma unroll
    for (int fj = 0; fj < 8; fj++) {
      int brow = fj * 16 + lo;
      bf[fj] = *(const bf16x8*)((const char*)Bcur + brow * 64 + ((g << 4) ^ rsw));
    }
#pragma unroll
    for (int fi = 0; fi < 4; fi++)
#pragma unroll
      for (int fj = 0; fj < 8; fj++)
        acc[fi][fj] = __builtin_amdgcn_mfma_f32_16x16x32_bf16(af[fi], bf[fj], acc[fi][fj], 0, 0, 0);
    if (it < 21) {
      ENDBAR();
      QKV_STAGE(it + 3, bsel);
    }
  }
#undef QKV_STAGE
#pragma unroll
  for (int fj = 0; fj < 8; fj++) {
    int mat = nb * 2 + (fj >> 2);  // 0..35
    int ty = mat / 12, h = mat % 12;
    int d = (fj & 3) * 16 + lo;
    if (ty < 2) {
#pragma unroll
      for (int fi = 0; fi < 4; fi++)
#pragma unroll
        for (int rr = 0; rr < 4; rr++) {
          int m = mb * 128 + w * 64 + fi * 16 + g * 4 + rr;
          int b = m >> 11, s = m & 2047;
          qkv[(size_t)ty * 6291456 + (size_t)(b * 12 + h) * 131072 + (size_t)s * 64 + d] =
              f2bf(acc[fi][fj][rr]);
        }
    } else {
      // v: transposed pair-packed per head: [32 tiles][64 d][32 kv-pairs] uints
#pragma unroll
      for (int fi = 0; fi < 4; fi++)
#pragma unroll
        for (int rr = 0; rr < 4; rr += 2) {
          int m = mb * 128 + w * 64 + fi * 16 + g * 4 + rr;
          int b = m >> 11, s = m & 2047;
          uint pk = cvt_pk(acc[fi][fj][rr], acc[fi][fj][rr + 1]);
          vtg[(size_t)(b * 12 + h) * 65536 + (s >> 6) * 2048 + d * 32 + ((s & 63) >> 1)] = pk;
        }
    }
  }
}

// ---------- causal flash attention (unchanged): fixed-max softmax, l via MFMA(ones).
__global__ __launch_bounds__(256, 3) void attn_fwd(const ushort* __restrict__ Qg,
                                                   const ushort* __restrict__ Kg,
                                                   const uint* __restrict__ Vtg,
                                                   ushort* __restrict__ ao) {
  __shared__ ushort Ksh[2][64 * 72];
  __shared__ uint Vsh[2][64 * 36];
  int x = blockIdx.x;
  int head = x % 48;
  int qb = 15 - x / 48;
  int T = 2 * qb + 2;
  int t = threadIdx.x, w = t >> 6, q31 = t & 31, hi = (t & 63) >> 5;
  const ushort* Q = Qg + (size_t)head * 131072;
  const ushort* K = Kg + (size_t)head * 131072;
  const uint* V = Vtg + (size_t)head * 65536;
  int qstart = qb * 128 + 32 * w;
  int qg = qstart + q31;
  bf16x8 qf[4];
#pragma unroll
  for (int s = 0; s < 4; s++)
    qf[s] = *(const bf16x8*)&Q[(size_t)qg * 64 + s * 16 + hi * 8];
  bf16x8 ones;
#pragma unroll
  for (int i = 0; i < 8; i++) ones[i] = (short)0x3F80;
  f32x16 oacc[2], lacc;
#pragma unroll
  for (int r = 0; r < 16; r++) { oacc[0][r] = 0.f; oacc[1][r] = 0.f; lacc[r] = 0.f; }
  int sr = t >> 3, sc = t & 7;
  bf16x8 kreg[2];
  u32x4 vreg[2];
#pragma unroll
  for (int i = 0; i < 2; i++) {
    kreg[i] = *(const bf16x8*)&K[(size_t)(i * 32 + sr) * 64 + sc * 8];
    vreg[i] = *(const u32x4*)&V[(i * 32 + sr) * 32 + sc * 4];
  }
#pragma unroll
  for (int i = 0; i < 2; i++) {
    *(bf16x8*)&Ksh[0][(i * 32 + sr) * 72 + sc * 8] = kreg[i];
    *(u32x4*)&Vsh[0][(i * 32 + sr) * 36 + sc * 4] = vreg[i];
  }
  for (int kb = 0; kb < T; kb++) {
    __syncthreads();
    if (kb + 1 < T) {
      int t1 = (kb + 1) * 64;
#pragma unroll
      for (int i = 0; i < 2; i++) {
        kreg[i] = *(const bf16x8*)&K[(size_t)(t1 + i * 32 + sr) * 64 + sc * 8];
        vreg[i] = *(const u32x4*)&V[(kb + 1) * 2048 + (i * 32 + sr) * 32 + sc * 4];
      }
    }
    int t0 = kb * 64;
    if (t0 <= qstart + 31) {
      const ushort* Kb = Ksh[kb & 1];
      const uint* Vb = Vsh[kb & 1];
      bool act1 = (t0 + 32 <= qstart + 31);
      f32x16 st0, st1;
#pragma unroll
      for (int r = 0; r < 16; r++) { st0[r] = 0.f; st1[r] = 0.f; }
#pragma unroll
      for (int s = 0; s < 4; s++) {
        bf16x8 kf = *(const bf16x8*)&Kb[q31 * 72 + s * 16 + hi * 8];
        st0 = __builtin_amdgcn_mfma_f32_32x32x16_bf16(kf, qf[s], st0, 0, 0, 0);
      }
      if (act1) {
#pragma unroll
        for (int s = 0; s < 4; s++) {
          bf16x8 kf = *(const bf16x8*)&Kb[(32 + q31) * 72 + s * 16 + hi * 8];
          st1 = __builtin_amdgcn_mfma_f32_32x32x16_bf16(kf, qf[s], st1, 0, 0, 0);
        }
      }
      if (t0 + 31 > qstart) {
        int base = t0 - qstart;
#pragma unroll
        for (int r = 0; r < 16; r++) {
          int crow = (r & 3) + 8 * (r >> 2) + 4 * hi;
          if (base + crow > q31) st0[r] = -3e38f;
        }
      }
      if (act1 && (t0 + 63 > qstart)) {
        int base = t0 + 32 - qstart;
#pragma unroll
        for (int r = 0; r < 16; r++) {
          int crow = (r & 3) + 8 * (r >> 2) + 4 * hi;
          if (base + crow > q31) st1[r] = -3e38f;
        }
      }
#pragma unroll
      for (int r = 0; r < 16; r++)
        st0[r] = __builtin_amdgcn_exp2f(st0[r] * SCALE_LOG2E);
      if (act1) {
#pragma unroll
        for (int r = 0; r < 16; r++)
          st1[r] = __builtin_amdgcn_exp2f(st1[r] * SCALE_LOG2E);
      }
      int ns = act1 ? 4 : 2;
      bf16x8 paf[4];
#pragma unroll
      for (int s = 0; s < 4; s++) {
        if (s < ns) {
          const f32x16& sv = (s < 2) ? st0 : st1;
          int rb = (s & 1) * 8;
          uint a = cvt_pk(sv[rb + 0], sv[rb + 1]);
          uint b2 = cvt_pk(sv[rb + 2], sv[rb + 3]);
          uint c = cvt_pk(sv[rb + 4], sv[rb + 5]);
          uint d = cvt_pk(sv[rb + 6], sv[rb + 7]);
          asm volatile("v_permlane32_swap_b32 %0, %1" : "+v"(a), "+v"(c));
          asm volatile("v_permlane32_swap_b32 %0, %1" : "+v"(b2), "+v"(d));
          u32x4 u4 = {a, b2, c, d};
          paf[s] = __builtin_bit_cast(bf16x8, u4);
        }
      }
#pragma unroll
      for (int s = 0; s < 4; s++) {
        if (s < ns) {
          lacc = __builtin_amdgcn_mfma_f32_32x32x16_bf16(paf[s], ones, lacc, 0, 0, 0);
#pragma unroll
          for (int dt = 0; dt < 2; dt++) {
            bf16x8 vf = *(const bf16x8*)&Vb[(dt * 32 + q31) * 36 + s * 8 + hi * 4];
            oacc[dt] = __builtin_amdgcn_mfma_f32_32x32x16_bf16(paf[s], vf, oacc[dt], 0, 0, 0);
          }
        }
      }
    }
    if (kb + 1 < T) {
      int b2 = (kb + 1) & 1;
#pragma unroll
      for (int i = 0; i < 2; i++) {
        *(bf16x8*)&Ksh[b2][(i * 32 + sr) * 72 + sc * 8] = kreg[i];
        *(u32x4*)&Vsh[b2][(i * 32 + sr) * 36 + sc * 4] = vreg[i];
      }
    }
  }
  int hh = head % 12, bb = head / 12;
#pragma unroll
  for (int dt = 0; dt < 2; dt++)
#pragma unroll
    for (int r = 0; r < 16; r++) {
      int qr = qstart + (r & 3) + 8 * (r >> 2) + 4 * hi;
      ao[(size_t)(bb * 2048 + qr) * 768 + hh * 64 + dt * 32 + q31] =
          f2bf(oacc[dt][r] / lacc[r]);
    }
}

// ---------- output projection: ao[8192,768] @ Wpt + bp -> out fp32.
// grid (64, 6), 128 thr = 2 waves; depth-3 pipeline, 8 loads/tile/thread.
__global__ __launch_bounds__(128, 2) void gemm_out(const ushort* __restrict__ A,
                                                   const ushort* __restrict__ Bt,
                                                   const float* __restrict__ bias,
                                                   float* __restrict__ out) {
  __shared__ ushort Ash[3][128 * 32];
  __shared__ ushort Bsh[3][128 * 32];
  int mb = blockIdx.x, nb = blockIdx.y;
  int t = threadIdx.x, w = t >> 6, lane = t & 63, lo = lane & 15, g = lane >> 4;
  const ushort* Ab = A + (size_t)mb * 128 * 768;
  const ushort* Bb = Bt + (size_t)nb * 128 * 768;
  f32x4 acc[4][8];
#pragma unroll
  for (int fi = 0; fi < 4; fi++)
#pragma unroll
    for (int fj = 0; fj < 8; fj++) acc[fi][fj] = (f32x4){0.f, 0.f, 0.f, 0.f};
  uint srow[4], ssc[4];
#pragma unroll
  for (int j = 0; j < 4; j++) {
    uint ci = j * 128 + t;
    srow[j] = ci >> 2;
    ssc[j] = ((ci & 3) ^ swz(ci >> 2)) << 4;
  }

#define OUT_STAGE(tile, bsel)                                                         \
  {                                                                                   \
    int e0 = (tile) * 32;                                                             \
    _Pragma("unroll")                                                                 \
    for (int j = 0; j < 4; j++) {                                                     \
      GLOAD16((const char*)(Ab + (size_t)srow[j] * 768 + e0) + ssc[j],                \
              &Ash[bsel][(j * 128 + w * 64) * 8]);                                    \
      GLOAD16((const char*)(Bb + (size_t)srow[j] * 768 + e0) + ssc[j],                \
              &Bsh[bsel][(j * 128 + w * 64) * 8]);                                    \
    }                                                                                 \
  }

  OUT_STAGE(0, 0);
  OUT_STAGE(1, 1);
  OUT_STAGE(2, 2);
  uint rsw = swz(lo) << 4;
  for (int it = 0; it < 24; ++it) {
    if (it <= 21) { WAITBAR(16); } else if (it == 22) { WAITBAR(8); } else { WAITBAR(0); }
    int bsel = it % 3;
    const ushort* Acur = Ash[bsel];
    const ushort* Bcur = Bsh[bsel];
    bf16x8 af[4], bf[8];
#pragma unroll
    for (int fi = 0; fi < 4; fi++) {
      int arow = w * 64 + fi * 16 + lo;
      af[fi] = *(const bf16x8*)((const char*)Acur + arow * 64 + ((g << 4) ^ rsw));
    }
#pragma unroll
    for (int fj = 0; fj < 8; fj++) {
      int brow = fj * 16 + lo;
      bf[fj] = *(const bf16x8*)((const char*)Bcur + brow * 64 + ((g << 4) ^ rsw));
    }
#pragma unroll
    for (int fi = 0; fi < 4; fi++)
#pragma unroll
      for (int fj = 0; fj < 8; fj++)
        acc[fi][fj] = __builtin_amdgcn_mfma_f32_16x16x32_bf16(af[fi], bf[fj], acc[fi][fj], 0, 0, 0);
    if (it < 21) {
      ENDBAR();
      OUT_STAGE(it + 3, bsel);
    }
  }
#undef OUT_STAGE
#pragma unroll
  for (int fj = 0; fj < 8; fj++) {
    int col = nb * 128 + fj * 16 + lo;
    float bv = bias[col];
#pragma unroll
    for (int fi = 0; fi < 4; fi++)
#pragma unroll
      for (int rr = 0; rr < 4; rr++) {
        int m = mb * 128 + w * 64 + fi * 16 + g * 4 + rr;
        out[(size_t)m * 768 + col] = acc[fi][fj][rr] + bv;
      }
  }
}

extern "C" void kernel_launch(void* const* d_in, const int* in_sizes, int n_in,
                              void* d_out, int out_size, void* d_ws, size_t ws_size,
                              hipStream_t stream) {
  const float* x  = (const float*)d_in[0];
  const float* Wq = (const float*)d_in[1];
  const float* Wk = (const float*)d_in[2];
  const float* Wv = (const float*)d_in[3];
  const float* Wp = (const float*)d_in[4];
  const float* bp = (const float*)d_in[5];
  float* out = (float*)d_out;
  ushort* ws = (ushort*)d_ws;

  ushort* xb  = ws + OFF_XB;
  ushort* wt  = ws + OFF_WT;
  ushort* wpt = ws + OFF_WPT;
  ushort* qkv = ws + OFF_QKV;                          // q, k
  uint*   vt  = (uint*)(ws + OFF_QKV + 2 * 6291456);   // packed-transposed v
  ushort* ao  = ws + OFF_AO;

  cvt_bf16<<<dim3(3072), 256, 0, stream>>>(x, xb, 786432);
  transpose_wqkv<<<dim3(12, 36), 256, 0, stream>>>(Wq, Wk, Wv, wt);
  transpose_w<<<dim3(144), 256, 0, stream>>>(Wp, wpt, 768, 768);

  gemm_qkv<<<dim3(64, 18), 128, 0, stream>>>(xb, wt, qkv, vt);
  attn_fwd<<<dim3(768), 256, 0, stream>>>(qkv, qkv + 6291456, vt, ao);
  gemm_out<<<dim3(64, 6), 128, 0, stream>>>(ao, wpt, bp, out);
}